// Round 12
// baseline (535.334 us; speedup 1.0000x reference)
//
#include <hip/hip_runtime.h>
#include <cmath>
#include <complex>
#include <algorithm>

// ---------------------------------------------------------------------------
// Problem constants: LMAX=2, NC=9, H=8, DQK=32, CV=16, K=8, U=25, N=2048, C=256
// ---------------------------------------------------------------------------

typedef _Float16 half8 __attribute__((ext_vector_type(8)));
typedef float float4v __attribute__((ext_vector_type(4)));

// ========================= host-side constant tables ========================
namespace {

using cd = std::complex<double>;

static double fct(int n) { double r = 1.0; for (int i = 2; i <= n; ++i) r *= i; return r; }

static double cg_coef(int j1, int m1, int j2, int m2, int j, int m) {
    if (m1 + m2 != m || j < std::abs(j1 - j2) || j > j1 + j2) return 0.0;
    double pref = std::sqrt((2 * j + 1) * fct(j + j1 - j2) * fct(j - j1 + j2) * fct(j1 + j2 - j) / fct(j1 + j2 + j + 1));
    pref *= std::sqrt(fct(j + m) * fct(j - m) * fct(j1 - m1) * fct(j1 + m1) * fct(j2 - m2) * fct(j2 + m2));
    double s = 0.0;
    for (int k = 0; k <= j1 + j2 - j; ++k) {
        int d0 = k, d1 = j1 + j2 - j - k, d2 = j1 - m1 - k, d3 = j2 + m2 - k, d4 = j - j2 + m1 + k, d5 = j - j1 - m2 + k;
        if (d0 < 0 || d1 < 0 || d2 < 0 || d3 < 0 || d4 < 0 || d5 < 0) continue;
        s += ((k & 1) ? -1.0 : 1.0) / (fct(d0) * fct(d1) * fct(d2) * fct(d3) * fct(d4) * fct(d5));
    }
    return pref * s;
}

static void umat(int l, cd u[5][5]) {
    for (int i = 0; i < 5; i++) for (int j = 0; j < 5; j++) u[i][j] = cd(0, 0);
    const double s = 1.0 / std::sqrt(2.0);
    for (int m = -l; m <= l; m++) {
        double sgn = (std::abs(m) & 1) ? -1.0 : 1.0;   // (-1)^m
        if (m > 0)      { u[l + m][l + m] = cd(sgn * s, 0); u[l + m][l - m] = cd(s, 0); }
        else if (m == 0){ u[l][l] = cd(1, 0); }
        else            { u[l + m][l + m] = cd(0, s);       u[l + m][l - m] = cd(0, -sgn * s); }
    }
}

static void real_cg_f(int l1, int l2, int L, double out[5][5][5]) {
    cd U1[5][5], U2[5][5], UL[5][5];
    umat(l1, U1); umat(l2, U2); umat(L, UL);
    const int n1 = 2 * l1 + 1, n2 = 2 * l2 + 1, n3 = 2 * L + 1;
    double cgt[5][5][5];
    for (int i1 = 0; i1 < n1; i1++) for (int i2 = 0; i2 < n2; i2++) for (int i3 = 0; i3 < n3; i3++)
        cgt[i1][i2][i3] = cg_coef(l1, i1 - l1, l2, i2 - l2, L, i3 - L);
    cd r[5][5][5];
    double nr = 0, ni = 0;
    for (int a1 = 0; a1 < n1; a1++) for (int b = 0; b < n2; b++) for (int c = 0; c < n3; c++) {
        cd acc(0, 0);
        for (int uu = 0; uu < n1; uu++) for (int vv = 0; vv < n2; vv++) for (int w = 0; w < n3; w++) {
            double cval = cgt[uu][vv][w];
            if (cval == 0.0) continue;
            acc += U1[a1][uu] * U2[b][vv] * std::conj(UL[c][w]) * cval;
        }
        r[a1][b][c] = acc;
        nr += acc.real() * acc.real();
        ni += acc.imag() * acc.imag();
    }
    const bool useRe = std::sqrt(nr) >= std::sqrt(ni);
    for (int a1 = 0; a1 < n1; a1++) for (int b = 0; b < n2; b++) for (int c = 0; c < n3; c++)
        out[a1][b][c] = useRe ? r[a1][b][c].real() : r[a1][b][c].imag();
}

// device constant buffer layout: YW[9*25] | RRED[9*81] | DIRS[25*3]  = 1029 floats
static float  h_const[1029];
static float* d_const_g = nullptr;

struct GlobalInit {
    GlobalInit() {
        const double PI = 3.14159265358979323846;
        const double gx[5] = {-0.9061798459386640, -0.5384693101056831, 0.0, 0.5384693101056831, 0.9061798459386640};
        const double gw[5] = { 0.23692688505618908, 0.47862867049936647, 0.5688888888888889, 0.47862867049936647, 0.23692688505618908};
        double YW[9][25], DIRS[25][3];
        for (int u = 0; u < 25; ++u) {
            const int it = u / 5, ip = u % 5;
            const double ct = gx[it], wq = gw[it] * (2.0 * PI / 5.0), ph = 2.0 * PI * ip / 5.0;
            const double st = std::sqrt(std::max(1.0 - ct * ct, 0.0));
            const double x = st * std::cos(ph), y = st * std::sin(ph), z = ct;
            DIRS[u][0] = x; DIRS[u][1] = y; DIRS[u][2] = z;
            double Y[9];
            Y[0] = 0.282095;           Y[1] = 0.488603 * y;      Y[2] = 0.488603 * z;
            Y[3] = 0.488603 * x;       Y[4] = 1.092548 * x * y;  Y[5] = 1.092548 * y * z;
            Y[6] = 0.315392 * (3 * z * z - 1); Y[7] = 1.092548 * x * z; Y[8] = 0.546274 * (x * x - y * y);
            for (int e = 0; e < 9; e++) YW[e][u] = Y[e] * wq;
        }
        double RRED[9][9][9];
        for (int i = 0; i < 9; i++) for (int j = 0; j < 9; j++) for (int k = 0; k < 9; k++) RRED[i][j][k] = 0.0;
        const int off[3] = {0, 1, 4};
        double cnt[3] = {0, 0, 0};
        double rc[5][5][5];
        for (int l1 = 0; l1 <= 2; l1++) for (int l2 = 0; l2 <= 2; l2++) {
            const int Llo = std::abs(l1 - l2), Lhi = std::min(l1 + l2, 2);
            for (int L = Llo; L <= Lhi; L++) {
                real_cg_f(l1, l2, L, rc);
                for (int i1 = 0; i1 < 2 * l1 + 1; i1++)
                    for (int i2 = 0; i2 < 2 * l2 + 1; i2++)
                        for (int i3 = 0; i3 < 2 * L + 1; i3++)
                            RRED[off[l1] + i1][off[l2] + i2][off[L] + i3] += rc[i1][i2][i3];
                cnt[L] += 1.0;
            }
        }
        for (int L = 0; L <= 2; L++) {
            const double dv = std::max(cnt[L], 1.0);
            for (int a1 = 0; a1 < 9; a1++) for (int b = 0; b < 9; b++)
                for (int k = 0; k < 2 * L + 1; k++) RRED[a1][b][off[L] + k] /= dv;
        }
        for (int e = 0; e < 9; e++) for (int u = 0; u < 25; u++) h_const[e * 25 + u] = (float)YW[e][u];
        for (int e = 0; e < 9; e++) for (int l = 0; l < 9; l++) for (int m = 0; m < 9; m++)
            h_const[225 + e * 81 + l * 9 + m] = (float)RRED[e][l][m];
        for (int u = 0; u < 25; u++) for (int ax = 0; ax < 3; ax++) h_const[954 + u * 3 + ax] = (float)DIRS[u][ax];
        if (hipMalloc((void**)&d_const_g, 1029 * sizeof(float)) == hipSuccess)
            hipMemcpy(d_const_g, h_const, 1029 * sizeof(float), hipMemcpyHostToDevice);
    }
} g_init;

} // namespace

// ============================== device kernels ==============================

// R[n][p][c]: p=0 -> feat(l=0); p=1 -> |l=1 block|; p=2 -> |l=2 block|
__global__ void radial_k(const float* __restrict__ feat, float* __restrict__ R) {
    const int n = blockIdx.x, c = threadIdx.x;
    const float* f = feat + (size_t)n * 9 * 256 + c;
    const float f0 = f[0];
    const float a1 = f[256], a2 = f[512], a3 = f[768];
    const float b1 = f[1024], b2 = f[1280], b3 = f[1536], b4 = f[1792], b5 = f[2048];
    const float r1 = sqrtf(a1 * a1 + a2 * a2 + a3 * a3 + 1e-8f);
    const float r2 = sqrtf(b1 * b1 + b2 * b2 + b3 * b3 + b4 * b4 + b5 * b5 + 1e-8f);
    float* o = R + (size_t)n * 768 + c;
    o[0] = f0; o[256] = r1; o[512] = r2;
}

// generic 64x64-tile f32 GEMM, C = A(MxK) @ B(KxN)
// mode 0 plain, 1 elu+1, 2 v-scatter f16 transposed, 4 sum-4-partials A with rZ scale,
// 5 elu+1 -> kfA fragment-ordered f16
__global__ __launch_bounds__(256) void gemm_k(const float* __restrict__ A, const float* __restrict__ B,
                                              float* __restrict__ Cv, int M, int N, int Kd, int mode,
                                              const float* __restrict__ rZ) {
    __shared__ float As[32][68];   // [k][row]
    __shared__ float Bs[32][68];   // [k][col]
    const int tid = threadIdx.x;
    const int tx = tid & 15, ty = tid >> 4;
    const int rb = blockIdx.y * 64, cb = blockIdx.x * 64;
    float acc[4][4];
#pragma unroll
    for (int i = 0; i < 4; i++) for (int j = 0; j < 4; j++) acc[i][j] = 0.f;
    for (int k0 = 0; k0 < Kd; k0 += 32) {
        __syncthreads();
#pragma unroll
        for (int i = 0; i < 2; i++) {
            const int idx = tid + i * 256;
            const int row = idx >> 3, kq = idx & 7;
            float4 av;
            if (mode == 4) {
                const float* Ap = A + (size_t)(rb + row) * Kd + k0 + kq * 4;
                const float4 a0 = *(const float4*)(Ap);
                const float4 a1 = *(const float4*)(Ap + 2359296);
                const float4 a2 = *(const float4*)(Ap + 4718592);
                const float4 a3 = *(const float4*)(Ap + 7077888);
                av.x = a0.x + a1.x + a2.x + a3.x;
                av.y = a0.y + a1.y + a2.y + a3.y;
                av.z = a0.z + a1.z + a2.z + a3.z;
                av.w = a0.w + a1.w + a2.w + a3.w;
                const int n = (rb + row) / 9;
                const int hh = (k0 + kq * 4) >> 4;
                const float rz = rZ[n * 8 + hh];
                av.x *= rz; av.y *= rz; av.z *= rz; av.w *= rz;
            } else {
                av = *(const float4*)(A + (size_t)(rb + row) * Kd + k0 + kq * 4);
            }
            As[kq * 4 + 0][row] = av.x; As[kq * 4 + 1][row] = av.y;
            As[kq * 4 + 2][row] = av.z; As[kq * 4 + 3][row] = av.w;
        }
#pragma unroll
        for (int i = 0; i < 2; i++) {
            const int idx = tid + i * 256;
            const int kr = idx >> 4, cq = idx & 15;
            *(float4*)&Bs[kr][cq * 4] = *(const float4*)(B + (size_t)(k0 + kr) * N + cb + cq * 4);
        }
        __syncthreads();
#pragma unroll 8
        for (int k = 0; k < 32; k++) {
            const float4 a = *(const float4*)&As[k][ty * 4];
            const float4 b = *(const float4*)&Bs[k][tx * 4];
            const float av[4] = {a.x, a.y, a.z, a.w};
            const float bv[4] = {b.x, b.y, b.z, b.w};
#pragma unroll
            for (int i = 0; i < 4; i++)
#pragma unroll
                for (int j = 0; j < 4; j++) acc[i][j] += av[i] * bv[j];
        }
    }
#pragma unroll
    for (int i = 0; i < 4; i++) {
        const int r = rb + ty * 4 + i;
#pragma unroll
        for (int j = 0; j < 4; j++) {
            const int cc2 = cb + tx * 4 + j;
            float val = acc[i][j];
            if (mode == 1 || mode == 5) val = (val > 0.f ? val : expf(val) - 1.f) + 1.f;
            if (mode == 2) {
                // v16T[(h*144 + c*9 + l)][n] f16
                const int n = r / 9, l = r - n * 9, hq = cc2 >> 4, cvq = cc2 & 15;
                _Float16* o = (_Float16*)Cv;
                o[((size_t)hq * 144 + cvq * 9 + l) * 2048 + n] = (_Float16)val;
            } else if (mode == 5) {
                // kfA[h][nb5][t][l15][j] fragment-ordered: cc2 = h*32+d, r = n
                const int hh = cc2 >> 5, dd = cc2 & 31, tt = dd >> 4, ll = dd & 15;
                _Float16* o = (_Float16*)Cv;
                o[(size_t)hh * 65536 + (size_t)(r >> 5) * 1024 + tt * 512 + ll * 32 + (r & 31)] = (_Float16)val;
            } else {
                Cv[(size_t)r * N + cc2] = val;
            }
        }
    }
}

// trigA[nb5][kkut][j] (f16, fragment-ordered) = cos/sin(kappa_kk * pos_n . dir_u)
//   kkut = (kk*25+u)*2+t (rows, padded to 512), nb5 = n>>5, j = n&31
__global__ void trig_k(const float* __restrict__ pos, const float* __restrict__ kappa,
                       const float* __restrict__ cst, _Float16* __restrict__ trigA) {
    const int n = blockIdx.x, t = threadIdx.x;
    if (t >= 200) return;
    const int kq = t / 25, u = t - kq * 25;
    const float* dirs = cst + 954;
    const float ph = kappa[kq] * (pos[n * 3] * dirs[u * 3] + pos[n * 3 + 1] * dirs[u * 3 + 1] + pos[n * 3 + 2] * dirs[u * 3 + 2]);
    float s, c;
    sincosf(ph, &s, &c);
    const int kkut = (kq * 25 + u) * 2;
    const size_t base = (size_t)(n >> 5) * 16384 + (n & 31);
    trigA[base + (size_t)kkut * 32] = (_Float16)c;
    trigA[base + (size_t)(kkut + 1) * 32] = (_Float16)s;
}

// ksum[h*32+d] = sum_n kfA[h][nb5][t][l15][j]; one block per (h,d)
__global__ void ksumT_k(const _Float16* __restrict__ kfA, float* __restrict__ ksum) {
    const int b = blockIdx.x;                       // h*32+d
    const int h = b >> 5, d = b & 31, t = d >> 4, l15 = d & 15;
    const int i = threadIdx.x;                      // 256
    const half8 v = *(const half8*)(kfA + (size_t)h * 65536 + (size_t)(i >> 2) * 1024 + t * 512 + l15 * 32 + (i & 3) * 8);
    float s = 0.f;
#pragma unroll
    for (int k = 0; k < 8; k++) s += (float)v[k];
#pragma unroll
    for (int off = 32; off > 0; off >>= 1) s += __shfl_down(s, off, 64);
    __shared__ float red[4];
    if ((i & 63) == 0) red[i >> 6] = s;
    __syncthreads();
    if (i == 0) ksum[b] = red[0] + red[1] + red[2] + red[3];
}

// rz[n][h] = 1 / (qf[n,h,:].ksum[h,:] + 1e-6)
__global__ void z_k(const float* __restrict__ qf, const float* __restrict__ ksum, float* __restrict__ rz) {
    const int idx = blockIdx.x * 256 + threadIdx.x;   // N*H = 16384
    const int n = idx >> 3, h = idx & 7;
    float s = 0.f;
#pragma unroll
    for (int d = 0; d < 32; d++) s += qf[(size_t)n * 256 + h * 32 + d] * ksum[h * 32 + d];
    rz[idx] = 1.0f / (s + 1e-6f);
}

// G[kk][h][u][l*9+m] = sum_e aE[e,h,kk] * YW[e,u] * RRED[e,l,m]
__global__ void g_k(const float* __restrict__ a, const float* __restrict__ cst, float* __restrict__ G) {
    const int kk = blockIdx.x & 7, h = blockIdx.x >> 3;
    __shared__ float ae[9];
    if (threadIdx.x < 9) {
        const int ldeg[9] = {0, 1, 1, 1, 2, 2, 2, 2, 2};
        ae[threadIdx.x] = a[ldeg[threadIdx.x] * 64 + h * 8 + kk];
    }
    __syncthreads();
    const float* yw = cst;
    const float* rred = cst + 225;
    for (int i = threadIdx.x; i < 25 * 81; i += 256) {
        const int u = i / 81, lm = i - u * 81;
        float s = 0.f;
#pragma unroll
        for (int e = 0; e < 9; e++) s += ae[e] * yw[e * 25 + u] * rred[e * 81 + lm];
        G[((size_t)(kk * 8 + h) * 25 + u) * 81 + lm] = s;
    }
}

// MFMA multipole, LDS-reduction K-split (R11) + XCD-h affinity (R12):
//   M16[kkut][h][cl*32+d] = sum_n trigA * kfA * v16T
// grid (8 h, 36 cl-quads, 4 row-blocks): linear block ID % 8 == h -> under
// round-robin dispatch all blocks of head h land on XCD h, so each XCD's hot
// read set is kfA[h] 128 KB + v16T[h] 576 KB + trigA 2 MB = 2.7 MB < 4 MB L2.
// block 512 = 8 waves; waves 0-3 rows rb..rb+127 over n in [0,1024),
// waves 4-7 same rows over n in [1024,2048); per-wave inner loop = R9 shape.
__global__ __launch_bounds__(512) void multipole_mm_k(const _Float16* __restrict__ trigA,
                                                      const _Float16* __restrict__ kfA,
                                                      const _Float16* __restrict__ v16T,
                                                      _Float16* __restrict__ M16) {
    const int h   = blockIdx.x;
    const int cl0 = blockIdx.y * 4;          // 4 cl per block -> 128 cols
    const int cb  = blockIdx.y * 128;
    const int rb  = blockIdx.z * 128;        // rows (kkut, padded to 512)
    const int tid = threadIdx.x;
    const int w = tid >> 6, lane = tid & 63;
    const int wlow = w & 3, nsp = w >> 2;    // row-group, n-split half
    const int l15 = lane & 15, quad = lane >> 4;

    const int r0 = rb + wlow * 32;

    float4v acc[2][8];
#pragma unroll
    for (int rt = 0; rt < 2; rt++)
#pragma unroll
        for (int s = 0; s < 8; s++) acc[rt][s] = float4v{0.f, 0.f, 0.f, 0.f};

    const _Float16* tb_ = trigA + (size_t)(r0 + l15) * 32 + quad * 8;           // + nb*512 (slab), af1 +512
    const _Float16* kb_ = kfA + (size_t)h * 65536 + l15 * 32 + quad * 8;        // + nb5*1024, kq1 +512
    const _Float16* vp  = v16T + ((size_t)h * 144 + cl0) * 2048 + quad * 8;     // + c*2048 + nb (broadcast)

    const int nb0 = nsp * 1024, nb1 = nb0 + 1024;
    for (int nb = nb0; nb < nb1; nb += 32) {
        const size_t ts = (size_t)nb * 512;          // nb5 * 16384
        const size_t ks = (size_t)(nb >> 5) * 1024;
        const half8 af0 = *(const half8*)(tb_ + ts);
        const half8 af1 = *(const half8*)(tb_ + ts + 512);
        const half8 kq0 = *(const half8*)(kb_ + ks);
        const half8 kq1 = *(const half8*)(kb_ + ks + 512);
        half8 vq[4];
#pragma unroll
        for (int c = 0; c < 4; c++) vq[c] = *(const half8*)(vp + (size_t)c * 2048 + nb);
#pragma unroll
        for (int c = 0; c < 4; c++) {
            const half8 b0 = kq0 * vq[c];
            const half8 b1 = kq1 * vq[c];
            acc[0][c * 2 + 0] = __builtin_amdgcn_mfma_f32_16x16x32_f16(af0, b0, acc[0][c * 2 + 0], 0, 0, 0);
            acc[0][c * 2 + 1] = __builtin_amdgcn_mfma_f32_16x16x32_f16(af0, b1, acc[0][c * 2 + 1], 0, 0, 0);
            acc[1][c * 2 + 0] = __builtin_amdgcn_mfma_f32_16x16x32_f16(af1, b0, acc[1][c * 2 + 0], 0, 0, 0);
            acc[1][c * 2 + 1] = __builtin_amdgcn_mfma_f32_16x16x32_f16(af1, b1, acc[1][c * 2 + 1], 0, 0, 0);
        }
    }
    // ---- cross-wave reduction: upper waves -> LDS, lower waves add ----
    __shared__ float red[4][64][64];   // [wlow][idx][lane], 64 KB, bank-conflict-free
    if (nsp == 1) {
#pragma unroll
        for (int rt = 0; rt < 2; rt++)
#pragma unroll
            for (int s = 0; s < 8; s++)
#pragma unroll
                for (int r = 0; r < 4; r++)
                    red[wlow][rt * 32 + s * 4 + r][lane] = acc[rt][s][r];
    }
    __syncthreads();
    if (nsp == 0) {
#pragma unroll
        for (int rt = 0; rt < 2; rt++)
#pragma unroll
            for (int s = 0; s < 8; s++)
#pragma unroll
                for (int r = 0; r < 4; r++)
                    acc[rt][s][r] += red[wlow][rt * 32 + s * 4 + r][lane];
        // epilogue: C fragment -> M16[kkut][h][col]
#pragma unroll
        for (int rt = 0; rt < 2; rt++)
#pragma unroll
            for (int c = 0; c < 4; c++)
#pragma unroll
                for (int half = 0; half < 2; half++)
#pragma unroll
                    for (int r = 0; r < 4; r++) {
                        const int row = r0 + rt * 16 + quad * 4 + r;
                        const int col = cb + c * 32 + half * 16 + l15;
                        M16[((size_t)row * 8 + h) * 4608 + col] = (_Float16)acc[rt][c * 2 + half][r];
                    }
    }
}

// MG[kt][h][ct*512 + quad*128 + l15*8 + j] (f16, fragment-ordered)
//   = sum_l M16[kt][h][(c*9+l)*32+d] * G[kk,h,u][l*9+m], cm=ct*16+l15, d=quad*8+j
__global__ __launch_bounds__(256) void fold_k(const _Float16* __restrict__ Mv, const float* __restrict__ G,
                                              _Float16* __restrict__ MG) {
    const int kt = blockIdx.x, h = blockIdx.y;
    const int tid = threadIdx.x;
    __shared__ float ms[144 * 33];   // [cl][d] padded 33
    __shared__ float gs[81];
    const _Float16* src = Mv + ((size_t)kt * 8 + h) * 4608;
    for (int i = tid; i < 4608; i += 256) {
        const int cl = i >> 5, d = i & 31;
        ms[cl * 33 + d] = (float)src[i];
    }
    const int kk = kt / 50, u = (kt >> 1) % 25;
    if (tid < 81) gs[tid] = G[(((size_t)kk * 8 + h) * 25 + u) * 81 + tid];
    __syncthreads();
    _Float16* dst = MG + ((size_t)kt * 8 + h) * 4608;
    for (int i = tid; i < 4608; i += 256) {
        const int ct = i >> 9, quad = (i >> 7) & 3, l15 = (i >> 3) & 15, j = i & 7;
        const int d = quad * 8 + j;
        const int cm = ct * 16 + l15, c = cm / 9, m = cm - c * 9;
        float s = 0.f;
#pragma unroll
        for (int l = 0; l < 9; l++) s += ms[(c * 9 + l) * 33 + d] * gs[l * 9 + m];
        dst[i] = (_Float16)s;
    }
}

// local stage via MFMA, barrier-free main loop; slab loads contiguous-1KB;
// epilogue transposes fragments through per-wave LDS so every store is a
// full 64 B line (one line per 4-lane cluster per instruction).
// grid (8 slots, 4 comboHi, 16 ngroups): combo = y*8+x = h*4+slice -> all 16
// ngroup blocks of one (h,slice) share linear-ID mod 8 -> same XCD, so each
// XCD's MG working set is 4 slabs = 3.7 MB < 4 MB L2 (R8: FETCH 117->20 MB).
__global__ __launch_bounds__(256) void mm_local_k(const float* __restrict__ qf, const _Float16* __restrict__ trigA,
                                                  const _Float16* __restrict__ MG, float* __restrict__ outp) {
    const int combo = blockIdx.y * 8 + blockIdx.x;
    const int h = combo >> 2;
    const int slice = combo & 3;
    const int n0 = blockIdx.z * 128;
    const int tid = threadIdx.x;
    const int w = tid >> 6, lane = tid & 63;
    const int l15 = lane & 15, quad = lane >> 4;

    const int nbase = n0 + w * 32;
    half8 qfr16[2];
#pragma unroll
    for (int rt = 0; rt < 2; rt++) {
        const int n = nbase + rt * 16 + l15;
        const float* qp = qf + (size_t)n * 256 + h * 32 + quad * 8;
#pragma unroll
        for (int j = 0; j < 8; j++) qfr16[rt][j] = (_Float16)qp[j];
    }
    float4v acc[2][9];
#pragma unroll
    for (int rt = 0; rt < 2; rt++)
#pragma unroll
        for (int ct = 0; ct < 9; ct++) acc[rt][ct] = float4v{0.f, 0.f, 0.f, 0.f};

    const int kt0 = slice * 100;
    const _Float16* slab0 = MG + (((size_t)kt0 * 8 + h) * 4608) + quad * 128 + l15 * 8;
    // trig scalars: trigA[nb5][kt][rt*16+l15]
    const _Float16* trg0 = trigA + (size_t)(nbase >> 5) * 16384 + (size_t)kt0 * 32 + l15;

    for (int kt = 0; kt < 100; kt++) {
        const _Float16* slab = slab0 + (size_t)kt * 8 * 4608;
        const _Float16 tv0 = trg0[(size_t)kt * 32];
        const _Float16 tv1 = trg0[(size_t)kt * 32 + 16];
        half8 tvv0, tvv1;
#pragma unroll
        for (int j = 0; j < 8; j++) { tvv0[j] = tv0; tvv1[j] = tv1; }
        const half8 af0 = tvv0 * qfr16[0];
        const half8 af1 = tvv1 * qfr16[1];
#pragma unroll
        for (int ct = 0; ct < 9; ct++) {
            const half8 b = *(const half8*)(slab + ct * 512);
            acc[0][ct] = __builtin_amdgcn_mfma_f32_16x16x32_f16(af0, b, acc[0][ct], 0, 0, 0);
            acc[1][ct] = __builtin_amdgcn_mfma_f32_16x16x32_f16(af1, b, acc[1][ct], 0, 0, 0);
        }
    }
    // epilogue: LDS transpose -> full-line stores into outp[slice][n][m][h][c]
    __shared__ float eb[4][16][148];   // per-wave [n_local][m*16+c], pad 148 (16B-aligned rows)
    float* dst = outp + (size_t)slice * 2359296;
    const int g4 = lane >> 2, sub = lane & 3;
#pragma unroll
    for (int rt = 0; rt < 2; rt++) {
        __syncthreads();
#pragma unroll
        for (int ct = 0; ct < 9; ct++) {
            const int cm = ct * 16 + l15;
            const int c = cm / 9, m = cm - c * 9;
#pragma unroll
            for (int r = 0; r < 4; r++)
                eb[w][quad * 4 + r][m * 16 + c] = acc[rt][ct][r];
        }
        __syncthreads();
#pragma unroll
        for (int s = 0; s < 9; s++) {
            const int li = s * 16 + g4;            // 0..143 line index
            const int nl = li / 9, m = li - nl * 9;
            const float4 v4 = *(const float4*)&eb[w][nl][m * 16 + sub * 4];
            const int n = nbase + rt * 16 + nl;
            *(float4*)&dst[((size_t)n * 9 + m) * 128 + h * 16 + sub * 4] = v4;
        }
    }
}

// ================================ launcher =================================
extern "C" void kernel_launch(void* const* d_in, const int* in_sizes, int n_in,
                              void* d_out, int out_size, void* d_ws, size_t ws_size,
                              hipStream_t stream) {
    const float* pos  = (const float*)d_in[0];
    const float* feat = (const float*)d_in[1];
    const float* Wq   = (const float*)d_in[2];
    const float* Wk   = (const float*)d_in[3];
    const float* Wv   = (const float*)d_in[4];
    const float* Wo   = (const float*)d_in[5];
    const float* a    = (const float*)d_in[6];
    const float* kap  = (const float*)d_in[7];
    float* out = (float*)d_out;
    float* ws = (float*)d_ws;

    // float-slot layout (~77.8 MB total)
    float* qf    = ws;                    // 524288
    float* kfAF  = qf + 524288;           // 262144 slots = kfA f16[8][64][2][512]
    float* vTF   = kfAF + 262144;         // 1179648 slots = v16T f16[1152*2048]
    float* trigF = vTF + 1179648;         // 524288 slots = trigA f16[64][512][32]
    float* ksum  = trigF + 524288;        // 256
    float* rz    = ksum + 256;            // 16384
    float* G     = rz + 16384;            // 129600
    float* M16F  = G + 129600;            // 9437184 slots = M16 f16[512*8*4608]; later outp[4][2359296]
    float* regX  = M16F + 9437184;        // 7372800 slots: R (first 1572864), later MG f16[400*8*4608]
    float* R     = regX;
    float* outp  = M16F;                  // overlay: M16 dead after fold_k; 4 partial buffers
    _Float16* trigA = (_Float16*)trigF;
    _Float16* kfA   = (_Float16*)kfAF;
    _Float16* v16T  = (_Float16*)vTF;
    _Float16* M16   = (_Float16*)M16F;
    _Float16* MG16  = (_Float16*)regX;

    const float* cst = d_const_g;

    hipLaunchKernelGGL(radial_k, dim3(2048), dim3(256), 0, stream, feat, R);
    hipLaunchKernelGGL(gemm_k, dim3(4, 32), dim3(256), 0, stream, R, Wq, qf, 2048, 256, 768, 1, rz);
    hipLaunchKernelGGL(gemm_k, dim3(4, 32), dim3(256), 0, stream, R, Wk, kfAF, 2048, 256, 768, 5, rz);
    hipLaunchKernelGGL(gemm_k, dim3(2, 288), dim3(256), 0, stream, feat, Wv, vTF, 18432, 128, 256, 2, rz);
    hipMemsetAsync(trigF, 0, 524288 * sizeof(float), stream);   // zero pad rows 400..511 (all slabs)
    hipLaunchKernelGGL(trig_k, dim3(2048), dim3(256), 0, stream, pos, kap, cst, trigA);
    hipLaunchKernelGGL(ksumT_k, dim3(256), dim3(256), 0, stream, kfA, ksum);
    hipLaunchKernelGGL(z_k, dim3(64), dim3(256), 0, stream, qf, ksum, rz);
    hipLaunchKernelGGL(g_k, dim3(64), dim3(256), 0, stream, a, cst, G);
    hipLaunchKernelGGL(multipole_mm_k, dim3(8, 36, 4), dim3(512), 0, stream, trigA, kfA, v16T, M16);
    hipLaunchKernelGGL(fold_k, dim3(400, 8), dim3(256), 0, stream, M16, G, MG16);
    hipLaunchKernelGGL(mm_local_k, dim3(8, 4, 16), dim3(256), 0, stream, qf, trigA, MG16, outp);
    hipLaunchKernelGGL(gemm_k, dim3(4, 288), dim3(256), 0, stream, outp, Wo, out, 18432, 256, 128, 4, rz);
}

// Round 13
// 460.073 us; speedup vs baseline: 1.1636x; 1.1636x over previous
//
#include <hip/hip_runtime.h>
#include <cmath>
#include <complex>
#include <algorithm>

// ---------------------------------------------------------------------------
// Problem constants: LMAX=2, NC=9, H=8, DQK=32, CV=16, K=8, U=25, N=2048, C=256
// ---------------------------------------------------------------------------

typedef _Float16 half8 __attribute__((ext_vector_type(8)));
typedef float float4v __attribute__((ext_vector_type(4)));

// ========================= host-side constant tables ========================
namespace {

using cd = std::complex<double>;

static double fct(int n) { double r = 1.0; for (int i = 2; i <= n; ++i) r *= i; return r; }

static double cg_coef(int j1, int m1, int j2, int m2, int j, int m) {
    if (m1 + m2 != m || j < std::abs(j1 - j2) || j > j1 + j2) return 0.0;
    double pref = std::sqrt((2 * j + 1) * fct(j + j1 - j2) * fct(j - j1 + j2) * fct(j1 + j2 - j) / fct(j1 + j2 + j + 1));
    pref *= std::sqrt(fct(j + m) * fct(j - m) * fct(j1 - m1) * fct(j1 + m1) * fct(j2 - m2) * fct(j2 + m2));
    double s = 0.0;
    for (int k = 0; k <= j1 + j2 - j; ++k) {
        int d0 = k, d1 = j1 + j2 - j - k, d2 = j1 - m1 - k, d3 = j2 + m2 - k, d4 = j - j2 + m1 + k, d5 = j - j1 - m2 + k;
        if (d0 < 0 || d1 < 0 || d2 < 0 || d3 < 0 || d4 < 0 || d5 < 0) continue;
        s += ((k & 1) ? -1.0 : 1.0) / (fct(d0) * fct(d1) * fct(d2) * fct(d3) * fct(d4) * fct(d5));
    }
    return pref * s;
}

static void umat(int l, cd u[5][5]) {
    for (int i = 0; i < 5; i++) for (int j = 0; j < 5; j++) u[i][j] = cd(0, 0);
    const double s = 1.0 / std::sqrt(2.0);
    for (int m = -l; m <= l; m++) {
        double sgn = (std::abs(m) & 1) ? -1.0 : 1.0;   // (-1)^m
        if (m > 0)      { u[l + m][l + m] = cd(sgn * s, 0); u[l + m][l - m] = cd(s, 0); }
        else if (m == 0){ u[l][l] = cd(1, 0); }
        else            { u[l + m][l + m] = cd(0, s);       u[l + m][l - m] = cd(0, -sgn * s); }
    }
}

static void real_cg_f(int l1, int l2, int L, double out[5][5][5]) {
    cd U1[5][5], U2[5][5], UL[5][5];
    umat(l1, U1); umat(l2, U2); umat(L, UL);
    const int n1 = 2 * l1 + 1, n2 = 2 * l2 + 1, n3 = 2 * L + 1;
    double cgt[5][5][5];
    for (int i1 = 0; i1 < n1; i1++) for (int i2 = 0; i2 < n2; i2++) for (int i3 = 0; i3 < n3; i3++)
        cgt[i1][i2][i3] = cg_coef(l1, i1 - l1, l2, i2 - l2, L, i3 - L);
    cd r[5][5][5];
    double nr = 0, ni = 0;
    for (int a1 = 0; a1 < n1; a1++) for (int b = 0; b < n2; b++) for (int c = 0; c < n3; c++) {
        cd acc(0, 0);
        for (int uu = 0; uu < n1; uu++) for (int vv = 0; vv < n2; vv++) for (int w = 0; w < n3; w++) {
            double cval = cgt[uu][vv][w];
            if (cval == 0.0) continue;
            acc += U1[a1][uu] * U2[b][vv] * std::conj(UL[c][w]) * cval;
        }
        r[a1][b][c] = acc;
        nr += acc.real() * acc.real();
        ni += acc.imag() * acc.imag();
    }
    const bool useRe = std::sqrt(nr) >= std::sqrt(ni);
    for (int a1 = 0; a1 < n1; a1++) for (int b = 0; b < n2; b++) for (int c = 0; c < n3; c++)
        out[a1][b][c] = useRe ? r[a1][b][c].real() : r[a1][b][c].imag();
}

// device constant buffer layout: YW[9*25] | RRED[9*81] | DIRS[25*3]  = 1029 floats
static float  h_const[1029];
static float* d_const_g = nullptr;

struct GlobalInit {
    GlobalInit() {
        const double PI = 3.14159265358979323846;
        const double gx[5] = {-0.9061798459386640, -0.5384693101056831, 0.0, 0.5384693101056831, 0.9061798459386640};
        const double gw[5] = { 0.23692688505618908, 0.47862867049936647, 0.5688888888888889, 0.47862867049936647, 0.23692688505618908};
        double YW[9][25], DIRS[25][3];
        for (int u = 0; u < 25; ++u) {
            const int it = u / 5, ip = u % 5;
            const double ct = gx[it], wq = gw[it] * (2.0 * PI / 5.0), ph = 2.0 * PI * ip / 5.0;
            const double st = std::sqrt(std::max(1.0 - ct * ct, 0.0));
            const double x = st * std::cos(ph), y = st * std::sin(ph), z = ct;
            DIRS[u][0] = x; DIRS[u][1] = y; DIRS[u][2] = z;
            double Y[9];
            Y[0] = 0.282095;           Y[1] = 0.488603 * y;      Y[2] = 0.488603 * z;
            Y[3] = 0.488603 * x;       Y[4] = 1.092548 * x * y;  Y[5] = 1.092548 * y * z;
            Y[6] = 0.315392 * (3 * z * z - 1); Y[7] = 1.092548 * x * z; Y[8] = 0.546274 * (x * x - y * y);
            for (int e = 0; e < 9; e++) YW[e][u] = Y[e] * wq;
        }
        double RRED[9][9][9];
        for (int i = 0; i < 9; i++) for (int j = 0; j < 9; j++) for (int k = 0; k < 9; k++) RRED[i][j][k] = 0.0;
        const int off[3] = {0, 1, 4};
        double cnt[3] = {0, 0, 0};
        double rc[5][5][5];
        for (int l1 = 0; l1 <= 2; l1++) for (int l2 = 0; l2 <= 2; l2++) {
            const int Llo = std::abs(l1 - l2), Lhi = std::min(l1 + l2, 2);
            for (int L = Llo; L <= Lhi; L++) {
                real_cg_f(l1, l2, L, rc);
                for (int i1 = 0; i1 < 2 * l1 + 1; i1++)
                    for (int i2 = 0; i2 < 2 * l2 + 1; i2++)
                        for (int i3 = 0; i3 < 2 * L + 1; i3++)
                            RRED[off[l1] + i1][off[l2] + i2][off[L] + i3] += rc[i1][i2][i3];
                cnt[L] += 1.0;
            }
        }
        for (int L = 0; L <= 2; L++) {
            const double dv = std::max(cnt[L], 1.0);
            for (int a1 = 0; a1 < 9; a1++) for (int b = 0; b < 9; b++)
                for (int k = 0; k < 2 * L + 1; k++) RRED[a1][b][off[L] + k] /= dv;
        }
        for (int e = 0; e < 9; e++) for (int u = 0; u < 25; u++) h_const[e * 25 + u] = (float)YW[e][u];
        for (int e = 0; e < 9; e++) for (int l = 0; l < 9; l++) for (int m = 0; m < 9; m++)
            h_const[225 + e * 81 + l * 9 + m] = (float)RRED[e][l][m];
        for (int u = 0; u < 25; u++) for (int ax = 0; ax < 3; ax++) h_const[954 + u * 3 + ax] = (float)DIRS[u][ax];
        if (hipMalloc((void**)&d_const_g, 1029 * sizeof(float)) == hipSuccess)
            hipMemcpy(d_const_g, h_const, 1029 * sizeof(float), hipMemcpyHostToDevice);
    }
} g_init;

} // namespace

// ============================== device kernels ==============================

// R[n][p][c]: p=0 -> feat(l=0); p=1 -> |l=1 block|; p=2 -> |l=2 block|
__global__ void radial_k(const float* __restrict__ feat, float* __restrict__ R) {
    const int n = blockIdx.x, c = threadIdx.x;
    const float* f = feat + (size_t)n * 9 * 256 + c;
    const float f0 = f[0];
    const float a1 = f[256], a2 = f[512], a3 = f[768];
    const float b1 = f[1024], b2 = f[1280], b3 = f[1536], b4 = f[1792], b5 = f[2048];
    const float r1 = sqrtf(a1 * a1 + a2 * a2 + a3 * a3 + 1e-8f);
    const float r2 = sqrtf(b1 * b1 + b2 * b2 + b3 * b3 + b4 * b4 + b5 * b5 + 1e-8f);
    float* o = R + (size_t)n * 768 + c;
    o[0] = f0; o[256] = r1; o[512] = r2;
}

// f16 MFMA GEMM, C = A(MxK) @ B(KxN), M%64==0, N%64==0, K%32==0.
// mode 1: elu+1 -> f32 C row-major
// mode 5: elu+1 -> kfA fragment-ordered f16
// mode 2: v16T f16 scatter
// mode 4: A = sum of 4 partial buffers (stride 2359296 floats) scaled by rZ[n][h];
//         plain f32 C row-major
// block 256 = 4 waves; wave w: rows rb+w*16..+15 x cols cb..cb+63 (4 subtiles)
__global__ __launch_bounds__(256) void mfma_gemm16_k(const float* __restrict__ A, const float* __restrict__ B,
                                                     float* __restrict__ Cv, int M, int N, int Kd, int mode,
                                                     const float* __restrict__ rZ) {
    __shared__ __align__(16) _Float16 Af[64 * 40];   // [row][k], stride 40 halves (80 B)
    __shared__ __align__(16) _Float16 Bf[64 * 40];   // [col][k]
    const int tid = threadIdx.x;
    const int w = tid >> 6, lane = tid & 63;
    const int l15 = lane & 15, quad = lane >> 4;
    const int rb = blockIdx.y * 64, cb = blockIdx.x * 64;
    const int sr = tid >> 2, sq = tid & 3;           // stager: row/col 0..63, k-quartet 0..3

    float4v acc[4];
#pragma unroll
    for (int s = 0; s < 4; s++) acc[s] = float4v{0.f, 0.f, 0.f, 0.f};

    for (int k0 = 0; k0 < Kd; k0 += 32) {
        __syncthreads();
        // ---- stage A (f32 -> f16, fragment order) ----
        {
            const float* Ap = A + (size_t)(rb + sr) * Kd + k0 + sq * 8;
            float4 a0, a1;
            if (mode == 4) {
                const float4 p00 = *(const float4*)(Ap);
                const float4 p01 = *(const float4*)(Ap + 4);
                const float4 p10 = *(const float4*)(Ap + 2359296);
                const float4 p11 = *(const float4*)(Ap + 2359296 + 4);
                const float4 p20 = *(const float4*)(Ap + 4718592);
                const float4 p21 = *(const float4*)(Ap + 4718592 + 4);
                const float4 p30 = *(const float4*)(Ap + 7077888);
                const float4 p31 = *(const float4*)(Ap + 7077888 + 4);
                const int n = (rb + sr) / 9;
                const int hh = (k0 + sq * 8) >> 4;
                const float rz = rZ[n * 8 + hh];
                a0.x = (p00.x + p10.x + p20.x + p30.x) * rz;
                a0.y = (p00.y + p10.y + p20.y + p30.y) * rz;
                a0.z = (p00.z + p10.z + p20.z + p30.z) * rz;
                a0.w = (p00.w + p10.w + p20.w + p30.w) * rz;
                a1.x = (p01.x + p11.x + p21.x + p31.x) * rz;
                a1.y = (p01.y + p11.y + p21.y + p31.y) * rz;
                a1.z = (p01.z + p11.z + p21.z + p31.z) * rz;
                a1.w = (p01.w + p11.w + p21.w + p31.w) * rz;
            } else {
                a0 = *(const float4*)(Ap);
                a1 = *(const float4*)(Ap + 4);
            }
            half8 hv;
            hv[0] = (_Float16)a0.x; hv[1] = (_Float16)a0.y; hv[2] = (_Float16)a0.z; hv[3] = (_Float16)a0.w;
            hv[4] = (_Float16)a1.x; hv[5] = (_Float16)a1.y; hv[6] = (_Float16)a1.z; hv[7] = (_Float16)a1.w;
            *(half8*)&Af[sr * 40 + sq * 8] = hv;
        }
        // ---- stage B (column gather, 4-line coalesced per instr; f32 -> f16) ----
        {
            const float* Bp = B + (size_t)(k0 + sq * 8) * N + cb + sr;
            half8 hv;
#pragma unroll
            for (int i = 0; i < 8; i++) hv[i] = (_Float16)Bp[(size_t)i * N];
            *(half8*)&Bf[sr * 40 + sq * 8] = hv;
        }
        __syncthreads();
        // ---- fragments + MFMA ----
        const half8 af = *(const half8*)&Af[(w * 16 + l15) * 40 + quad * 8];
#pragma unroll
        for (int s = 0; s < 4; s++) {
            const half8 bf = *(const half8*)&Bf[(s * 16 + l15) * 40 + quad * 8];
            acc[s] = __builtin_amdgcn_mfma_f32_16x16x32_f16(af, bf, acc[s], 0, 0, 0);
        }
    }
    // ---- epilogue: C fragment (row = rb+w*16+quad*4+r, col = cb+s*16+l15) ----
#pragma unroll
    for (int s = 0; s < 4; s++) {
#pragma unroll
        for (int r = 0; r < 4; r++) {
            const int row = rb + w * 16 + quad * 4 + r;
            const int col = cb + s * 16 + l15;
            float val = acc[s][r];
            if (mode == 1 || mode == 5) val = (val > 0.f ? val : expf(val) - 1.f) + 1.f;
            if (mode == 2) {
                // v16T[(h*144 + c*9 + l)][n] f16
                const int n = row / 9, l = row - n * 9, hq = col >> 4, cvq = col & 15;
                _Float16* o = (_Float16*)Cv;
                o[((size_t)hq * 144 + cvq * 9 + l) * 2048 + n] = (_Float16)val;
            } else if (mode == 5) {
                // kfA[h][nb5][t][l15][j] fragment-ordered: col = h*32+d, row = n
                const int hh = col >> 5, dd = col & 31, tt = dd >> 4, ll = dd & 15;
                _Float16* o = (_Float16*)Cv;
                o[(size_t)hh * 65536 + (size_t)(row >> 5) * 1024 + tt * 512 + ll * 32 + (row & 31)] = (_Float16)val;
            } else {
                Cv[(size_t)row * N + col] = val;
            }
        }
    }
}

// trigA[nb5][kkut][j] (f16, fragment-ordered) = cos/sin(kappa_kk * pos_n . dir_u)
//   kkut = (kk*25+u)*2+t (rows, padded to 512), nb5 = n>>5, j = n&31
__global__ void trig_k(const float* __restrict__ pos, const float* __restrict__ kappa,
                       const float* __restrict__ cst, _Float16* __restrict__ trigA) {
    const int n = blockIdx.x, t = threadIdx.x;
    if (t >= 200) return;
    const int kq = t / 25, u = t - kq * 25;
    const float* dirs = cst + 954;
    const float ph = kappa[kq] * (pos[n * 3] * dirs[u * 3] + pos[n * 3 + 1] * dirs[u * 3 + 1] + pos[n * 3 + 2] * dirs[u * 3 + 2]);
    float s, c;
    sincosf(ph, &s, &c);
    const int kkut = (kq * 25 + u) * 2;
    const size_t base = (size_t)(n >> 5) * 16384 + (n & 31);
    trigA[base + (size_t)kkut * 32] = (_Float16)c;
    trigA[base + (size_t)(kkut + 1) * 32] = (_Float16)s;
}

// ksum[h*32+d] = sum_n kfA[h][nb5][t][l15][j]; one block per (h,d)
__global__ void ksumT_k(const _Float16* __restrict__ kfA, float* __restrict__ ksum) {
    const int b = blockIdx.x;                       // h*32+d
    const int h = b >> 5, d = b & 31, t = d >> 4, l15 = d & 15;
    const int i = threadIdx.x;                      // 256
    const half8 v = *(const half8*)(kfA + (size_t)h * 65536 + (size_t)(i >> 2) * 1024 + t * 512 + l15 * 32 + (i & 3) * 8);
    float s = 0.f;
#pragma unroll
    for (int k = 0; k < 8; k++) s += (float)v[k];
#pragma unroll
    for (int off = 32; off > 0; off >>= 1) s += __shfl_down(s, off, 64);
    __shared__ float red[4];
    if ((i & 63) == 0) red[i >> 6] = s;
    __syncthreads();
    if (i == 0) ksum[b] = red[0] + red[1] + red[2] + red[3];
}

// rz[n][h] = 1 / (qf[n,h,:].ksum[h,:] + 1e-6)
__global__ void z_k(const float* __restrict__ qf, const float* __restrict__ ksum, float* __restrict__ rz) {
    const int idx = blockIdx.x * 256 + threadIdx.x;   // N*H = 16384
    const int n = idx >> 3, h = idx & 7;
    float s = 0.f;
#pragma unroll
    for (int d = 0; d < 32; d++) s += qf[(size_t)n * 256 + h * 32 + d] * ksum[h * 32 + d];
    rz[idx] = 1.0f / (s + 1e-6f);
}

// G[kk][h][u][l*9+m] = sum_e aE[e,h,kk] * YW[e,u] * RRED[e,l,m]
__global__ void g_k(const float* __restrict__ a, const float* __restrict__ cst, float* __restrict__ G) {
    const int kk = blockIdx.x & 7, h = blockIdx.x >> 3;
    __shared__ float ae[9];
    if (threadIdx.x < 9) {
        const int ldeg[9] = {0, 1, 1, 1, 2, 2, 2, 2, 2};
        ae[threadIdx.x] = a[ldeg[threadIdx.x] * 64 + h * 8 + kk];
    }
    __syncthreads();
    const float* yw = cst;
    const float* rred = cst + 225;
    for (int i = threadIdx.x; i < 25 * 81; i += 256) {
        const int u = i / 81, lm = i - u * 81;
        float s = 0.f;
#pragma unroll
        for (int e = 0; e < 9; e++) s += ae[e] * yw[e * 25 + u] * rred[e * 81 + lm];
        G[((size_t)(kk * 8 + h) * 25 + u) * 81 + lm] = s;
    }
}

// MFMA multipole, LDS-reduction K-split (R11) + XCD-h affinity (R12):
//   M16[kkut][h][cl*32+d] = sum_n trigA * kfA * v16T
// grid (8 h, 36 cl-quads, 4 row-blocks): linear block ID % 8 == h -> all blocks
// of head h land on XCD h; per-XCD hot read set 2.7 MB < 4 MB L2 (R12: FETCH 31->14 MB).
// block 512 = 8 waves; waves 0-3 rows rb..rb+127 over n in [0,1024),
// waves 4-7 same rows over n in [1024,2048).
__global__ __launch_bounds__(512) void multipole_mm_k(const _Float16* __restrict__ trigA,
                                                      const _Float16* __restrict__ kfA,
                                                      const _Float16* __restrict__ v16T,
                                                      _Float16* __restrict__ M16) {
    const int h   = blockIdx.x;
    const int cl0 = blockIdx.y * 4;          // 4 cl per block -> 128 cols
    const int cb  = blockIdx.y * 128;
    const int rb  = blockIdx.z * 128;        // rows (kkut, padded to 512)
    const int tid = threadIdx.x;
    const int w = tid >> 6, lane = tid & 63;
    const int wlow = w & 3, nsp = w >> 2;    // row-group, n-split half
    const int l15 = lane & 15, quad = lane >> 4;

    const int r0 = rb + wlow * 32;

    float4v acc[2][8];
#pragma unroll
    for (int rt = 0; rt < 2; rt++)
#pragma unroll
        for (int s = 0; s < 8; s++) acc[rt][s] = float4v{0.f, 0.f, 0.f, 0.f};

    const _Float16* tb_ = trigA + (size_t)(r0 + l15) * 32 + quad * 8;           // + nb*512 (slab), af1 +512
    const _Float16* kb_ = kfA + (size_t)h * 65536 + l15 * 32 + quad * 8;        // + nb5*1024, kq1 +512
    const _Float16* vp  = v16T + ((size_t)h * 144 + cl0) * 2048 + quad * 8;     // + c*2048 + nb (broadcast)

    const int nb0 = nsp * 1024, nb1 = nb0 + 1024;
    for (int nb = nb0; nb < nb1; nb += 32) {
        const size_t ts = (size_t)nb * 512;          // nb5 * 16384
        const size_t ks = (size_t)(nb >> 5) * 1024;
        const half8 af0 = *(const half8*)(tb_ + ts);
        const half8 af1 = *(const half8*)(tb_ + ts + 512);
        const half8 kq0 = *(const half8*)(kb_ + ks);
        const half8 kq1 = *(const half8*)(kb_ + ks + 512);
        half8 vq[4];
#pragma unroll
        for (int c = 0; c < 4; c++) vq[c] = *(const half8*)(vp + (size_t)c * 2048 + nb);
#pragma unroll
        for (int c = 0; c < 4; c++) {
            const half8 b0 = kq0 * vq[c];
            const half8 b1 = kq1 * vq[c];
            acc[0][c * 2 + 0] = __builtin_amdgcn_mfma_f32_16x16x32_f16(af0, b0, acc[0][c * 2 + 0], 0, 0, 0);
            acc[0][c * 2 + 1] = __builtin_amdgcn_mfma_f32_16x16x32_f16(af0, b1, acc[0][c * 2 + 1], 0, 0, 0);
            acc[1][c * 2 + 0] = __builtin_amdgcn_mfma_f32_16x16x32_f16(af1, b0, acc[1][c * 2 + 0], 0, 0, 0);
            acc[1][c * 2 + 1] = __builtin_amdgcn_mfma_f32_16x16x32_f16(af1, b1, acc[1][c * 2 + 1], 0, 0, 0);
        }
    }
    // ---- cross-wave reduction: upper waves -> LDS, lower waves add ----
    __shared__ float red[4][64][64];   // [wlow][idx][lane], 64 KB, bank-conflict-free
    if (nsp == 1) {
#pragma unroll
        for (int rt = 0; rt < 2; rt++)
#pragma unroll
            for (int s = 0; s < 8; s++)
#pragma unroll
                for (int r = 0; r < 4; r++)
                    red[wlow][rt * 32 + s * 4 + r][lane] = acc[rt][s][r];
    }
    __syncthreads();
    if (nsp == 0) {
#pragma unroll
        for (int rt = 0; rt < 2; rt++)
#pragma unroll
            for (int s = 0; s < 8; s++)
#pragma unroll
                for (int r = 0; r < 4; r++)
                    acc[rt][s][r] += red[wlow][rt * 32 + s * 4 + r][lane];
        // epilogue: C fragment -> M16[kkut][h][col]
#pragma unroll
        for (int rt = 0; rt < 2; rt++)
#pragma unroll
            for (int c = 0; c < 4; c++)
#pragma unroll
                for (int half = 0; half < 2; half++)
#pragma unroll
                    for (int r = 0; r < 4; r++) {
                        const int row = r0 + rt * 16 + quad * 4 + r;
                        const int col = cb + c * 32 + half * 16 + l15;
                        M16[((size_t)row * 8 + h) * 4608 + col] = (_Float16)acc[rt][c * 2 + half][r];
                    }
    }
}

// MG[kt][h][ct*512 + quad*128 + l15*8 + j] (f16, fragment-ordered)
//   = sum_l M16[kt][h][(c*9+l)*32+d] * G[kk,h,u][l*9+m], cm=ct*16+l15, d=quad*8+j
__global__ __launch_bounds__(256) void fold_k(const _Float16* __restrict__ Mv, const float* __restrict__ G,
                                              _Float16* __restrict__ MG) {
    const int kt = blockIdx.x, h = blockIdx.y;
    const int tid = threadIdx.x;
    __shared__ float ms[144 * 33];   // [cl][d] padded 33
    __shared__ float gs[81];
    const _Float16* src = Mv + ((size_t)kt * 8 + h) * 4608;
    for (int i = tid; i < 4608; i += 256) {
        const int cl = i >> 5, d = i & 31;
        ms[cl * 33 + d] = (float)src[i];
    }
    const int kk = kt / 50, u = (kt >> 1) % 25;
    if (tid < 81) gs[tid] = G[(((size_t)kk * 8 + h) * 25 + u) * 81 + tid];
    __syncthreads();
    _Float16* dst = MG + ((size_t)kt * 8 + h) * 4608;
    for (int i = tid; i < 4608; i += 256) {
        const int ct = i >> 9, quad = (i >> 7) & 3, l15 = (i >> 3) & 15, j = i & 7;
        const int d = quad * 8 + j;
        const int cm = ct * 16 + l15, c = cm / 9, m = cm - c * 9;
        float s = 0.f;
#pragma unroll
        for (int l = 0; l < 9; l++) s += ms[(c * 9 + l) * 33 + d] * gs[l * 9 + m];
        dst[i] = (_Float16)s;
    }
}

// local stage via MFMA, barrier-free main loop; slab loads contiguous-1KB;
// epilogue transposes fragments through per-wave LDS so every store is a
// full 64 B line. grid (8 slots, 4 comboHi, 16 ngroups): combo = h*4+slice ->
// same XCD per (h,slice); per-XCD MG set 3.7 MB < 4 MB L2 (R8).
__global__ __launch_bounds__(256) void mm_local_k(const float* __restrict__ qf, const _Float16* __restrict__ trigA,
                                                  const _Float16* __restrict__ MG, float* __restrict__ outp) {
    const int combo = blockIdx.y * 8 + blockIdx.x;
    const int h = combo >> 2;
    const int slice = combo & 3;
    const int n0 = blockIdx.z * 128;
    const int tid = threadIdx.x;
    const int w = tid >> 6, lane = tid & 63;
    const int l15 = lane & 15, quad = lane >> 4;

    const int nbase = n0 + w * 32;
    half8 qfr16[2];
#pragma unroll
    for (int rt = 0; rt < 2; rt++) {
        const int n = nbase + rt * 16 + l15;
        const float* qp = qf + (size_t)n * 256 + h * 32 + quad * 8;
#pragma unroll
        for (int j = 0; j < 8; j++) qfr16[rt][j] = (_Float16)qp[j];
    }
    float4v acc[2][9];
#pragma unroll
    for (int rt = 0; rt < 2; rt++)
#pragma unroll
        for (int ct = 0; ct < 9; ct++) acc[rt][ct] = float4v{0.f, 0.f, 0.f, 0.f};

    const int kt0 = slice * 100;
    const _Float16* slab0 = MG + (((size_t)kt0 * 8 + h) * 4608) + quad * 128 + l15 * 8;
    // trig scalars: trigA[nb5][kt][rt*16+l15]
    const _Float16* trg0 = trigA + (size_t)(nbase >> 5) * 16384 + (size_t)kt0 * 32 + l15;

    for (int kt = 0; kt < 100; kt++) {
        const _Float16* slab = slab0 + (size_t)kt * 8 * 4608;
        const _Float16 tv0 = trg0[(size_t)kt * 32];
        const _Float16 tv1 = trg0[(size_t)kt * 32 + 16];
        half8 tvv0, tvv1;
#pragma unroll
        for (int j = 0; j < 8; j++) { tvv0[j] = tv0; tvv1[j] = tv1; }
        const half8 af0 = tvv0 * qfr16[0];
        const half8 af1 = tvv1 * qfr16[1];
#pragma unroll
        for (int ct = 0; ct < 9; ct++) {
            const half8 b = *(const half8*)(slab + ct * 512);
            acc[0][ct] = __builtin_amdgcn_mfma_f32_16x16x32_f16(af0, b, acc[0][ct], 0, 0, 0);
            acc[1][ct] = __builtin_amdgcn_mfma_f32_16x16x32_f16(af1, b, acc[1][ct], 0, 0, 0);
        }
    }
    // epilogue: LDS transpose -> full-line stores into outp[slice][n][m][h][c]
    __shared__ float eb[4][16][148];   // per-wave [n_local][m*16+c], pad 148 (16B-aligned rows)
    float* dst = outp + (size_t)slice * 2359296;
    const int g4 = lane >> 2, sub = lane & 3;
#pragma unroll
    for (int rt = 0; rt < 2; rt++) {
        __syncthreads();
#pragma unroll
        for (int ct = 0; ct < 9; ct++) {
            const int cm = ct * 16 + l15;
            const int c = cm / 9, m = cm - c * 9;
#pragma unroll
            for (int r = 0; r < 4; r++)
                eb[w][quad * 4 + r][m * 16 + c] = acc[rt][ct][r];
        }
        __syncthreads();
#pragma unroll
        for (int s = 0; s < 9; s++) {
            const int li = s * 16 + g4;            // 0..143 line index
            const int nl = li / 9, m = li - nl * 9;
            const float4 v4 = *(const float4*)&eb[w][nl][m * 16 + sub * 4];
            const int n = nbase + rt * 16 + nl;
            *(float4*)&dst[((size_t)n * 9 + m) * 128 + h * 16 + sub * 4] = v4;
        }
    }
}

// ================================ launcher =================================
extern "C" void kernel_launch(void* const* d_in, const int* in_sizes, int n_in,
                              void* d_out, int out_size, void* d_ws, size_t ws_size,
                              hipStream_t stream) {
    const float* pos  = (const float*)d_in[0];
    const float* feat = (const float*)d_in[1];
    const float* Wq   = (const float*)d_in[2];
    const float* Wk   = (const float*)d_in[3];
    const float* Wv   = (const float*)d_in[4];
    const float* Wo   = (const float*)d_in[5];
    const float* a    = (const float*)d_in[6];
    const float* kap  = (const float*)d_in[7];
    float* out = (float*)d_out;
    float* ws = (float*)d_ws;

    // float-slot layout (~77.8 MB total)
    float* qf    = ws;                    // 524288
    float* kfAF  = qf + 524288;           // 262144 slots = kfA f16[8][64][2][512]
    float* vTF   = kfAF + 262144;         // 1179648 slots = v16T f16[1152*2048]
    float* trigF = vTF + 1179648;         // 524288 slots = trigA f16[64][512][32]
    float* ksum  = trigF + 524288;        // 256
    float* rz    = ksum + 256;            // 16384
    float* G     = rz + 16384;            // 129600
    float* M16F  = G + 129600;            // 9437184 slots = M16 f16[512*8*4608]; later outp[4][2359296]
    float* regX  = M16F + 9437184;        // 7372800 slots: R (first 1572864), later MG f16[400*8*4608]
    float* R     = regX;
    float* outp  = M16F;                  // overlay: M16 dead after fold_k; 4 partial buffers
    _Float16* trigA = (_Float16*)trigF;
    _Float16* kfA   = (_Float16*)kfAF;
    _Float16* v16T  = (_Float16*)vTF;
    _Float16* M16   = (_Float16*)M16F;
    _Float16* MG16  = (_Float16*)regX;

    const float* cst = d_const_g;

    hipLaunchKernelGGL(radial_k, dim3(2048), dim3(256), 0, stream, feat, R);
    hipLaunchKernelGGL(mfma_gemm16_k, dim3(4, 32), dim3(256), 0, stream, R, Wq, qf, 2048, 256, 768, 1, rz);
    hipLaunchKernelGGL(mfma_gemm16_k, dim3(4, 32), dim3(256), 0, stream, R, Wk, kfAF, 2048, 256, 768, 5, rz);
    hipLaunchKernelGGL(mfma_gemm16_k, dim3(2, 288), dim3(256), 0, stream, feat, Wv, vTF, 18432, 128, 256, 2, rz);
    hipMemsetAsync(trigF, 0, 524288 * sizeof(float), stream);   // zero pad rows 400..511 (all slabs)
    hipLaunchKernelGGL(trig_k, dim3(2048), dim3(256), 0, stream, pos, kap, cst, trigA);
    hipLaunchKernelGGL(ksumT_k, dim3(256), dim3(256), 0, stream, kfA, ksum);
    hipLaunchKernelGGL(z_k, dim3(64), dim3(256), 0, stream, qf, ksum, rz);
    hipLaunchKernelGGL(g_k, dim3(64), dim3(256), 0, stream, a, cst, G);
    hipLaunchKernelGGL(multipole_mm_k, dim3(8, 36, 4), dim3(512), 0, stream, trigA, kfA, v16T, M16);
    hipLaunchKernelGGL(fold_k, dim3(400, 8), dim3(256), 0, stream, M16, G, MG16);
    hipLaunchKernelGGL(mm_local_k, dim3(8, 4, 16), dim3(256), 0, stream, qf, trigA, MG16, outp);
    hipLaunchKernelGGL(mfma_gemm16_k, dim3(4, 288), dim3(256), 0, stream, outp, Wo, out, 18432, 256, 128, 4, rz);
}

// Round 14
// 433.709 us; speedup vs baseline: 1.2343x; 1.0608x over previous
//
#include <hip/hip_runtime.h>
#include <cmath>
#include <complex>
#include <algorithm>

// ---------------------------------------------------------------------------
// Problem constants: LMAX=2, NC=9, H=8, DQK=32, CV=16, K=8, U=25, N=2048, C=256
// ---------------------------------------------------------------------------

typedef _Float16 half8 __attribute__((ext_vector_type(8)));
typedef float float4v __attribute__((ext_vector_type(4)));

// ========================= host-side constant tables ========================
namespace {

using cd = std::complex<double>;

static double fct(int n) { double r = 1.0; for (int i = 2; i <= n; ++i) r *= i; return r; }

static double cg_coef(int j1, int m1, int j2, int m2, int j, int m) {
    if (m1 + m2 != m || j < std::abs(j1 - j2) || j > j1 + j2) return 0.0;
    double pref = std::sqrt((2 * j + 1) * fct(j + j1 - j2) * fct(j - j1 + j2) * fct(j1 + j2 - j) / fct(j1 + j2 + j + 1));
    pref *= std::sqrt(fct(j + m) * fct(j - m) * fct(j1 - m1) * fct(j1 + m1) * fct(j2 - m2) * fct(j2 + m2));
    double s = 0.0;
    for (int k = 0; k <= j1 + j2 - j; ++k) {
        int d0 = k, d1 = j1 + j2 - j - k, d2 = j1 - m1 - k, d3 = j2 + m2 - k, d4 = j - j2 + m1 + k, d5 = j - j1 - m2 + k;
        if (d0 < 0 || d1 < 0 || d2 < 0 || d3 < 0 || d4 < 0 || d5 < 0) continue;
        s += ((k & 1) ? -1.0 : 1.0) / (fct(d0) * fct(d1) * fct(d2) * fct(d3) * fct(d4) * fct(d5));
    }
    return pref * s;
}

static void umat(int l, cd u[5][5]) {
    for (int i = 0; i < 5; i++) for (int j = 0; j < 5; j++) u[i][j] = cd(0, 0);
    const double s = 1.0 / std::sqrt(2.0);
    for (int m = -l; m <= l; m++) {
        double sgn = (std::abs(m) & 1) ? -1.0 : 1.0;   // (-1)^m
        if (m > 0)      { u[l + m][l + m] = cd(sgn * s, 0); u[l + m][l - m] = cd(s, 0); }
        else if (m == 0){ u[l][l] = cd(1, 0); }
        else            { u[l + m][l + m] = cd(0, s);       u[l + m][l - m] = cd(0, -sgn * s); }
    }
}

static void real_cg_f(int l1, int l2, int L, double out[5][5][5]) {
    cd U1[5][5], U2[5][5], UL[5][5];
    umat(l1, U1); umat(l2, U2); umat(L, UL);
    const int n1 = 2 * l1 + 1, n2 = 2 * l2 + 1, n3 = 2 * L + 1;
    double cgt[5][5][5];
    for (int i1 = 0; i1 < n1; i1++) for (int i2 = 0; i2 < n2; i2++) for (int i3 = 0; i3 < n3; i3++)
        cgt[i1][i2][i3] = cg_coef(l1, i1 - l1, l2, i2 - l2, L, i3 - L);
    cd r[5][5][5];
    double nr = 0, ni = 0;
    for (int a1 = 0; a1 < n1; a1++) for (int b = 0; b < n2; b++) for (int c = 0; c < n3; c++) {
        cd acc(0, 0);
        for (int uu = 0; uu < n1; uu++) for (int vv = 0; vv < n2; vv++) for (int w = 0; w < n3; w++) {
            double cval = cgt[uu][vv][w];
            if (cval == 0.0) continue;
            acc += U1[a1][uu] * U2[b][vv] * std::conj(UL[c][w]) * cval;
        }
        r[a1][b][c] = acc;
        nr += acc.real() * acc.real();
        ni += acc.imag() * acc.imag();
    }
    const bool useRe = std::sqrt(nr) >= std::sqrt(ni);
    for (int a1 = 0; a1 < n1; a1++) for (int b = 0; b < n2; b++) for (int c = 0; c < n3; c++)
        out[a1][b][c] = useRe ? r[a1][b][c].real() : r[a1][b][c].imag();
}

// device constant buffer layout: YW[9*25] | RRED[9*81] | DIRS[25*3]  = 1029 floats
static float  h_const[1029];
static float* d_const_g = nullptr;

struct GlobalInit {
    GlobalInit() {
        const double PI = 3.14159265358979323846;
        const double gx[5] = {-0.9061798459386640, -0.5384693101056831, 0.0, 0.5384693101056831, 0.9061798459386640};
        const double gw[5] = { 0.23692688505618908, 0.47862867049936647, 0.5688888888888889, 0.47862867049936647, 0.23692688505618908};
        double YW[9][25], DIRS[25][3];
        for (int u = 0; u < 25; ++u) {
            const int it = u / 5, ip = u % 5;
            const double ct = gx[it], wq = gw[it] * (2.0 * PI / 5.0), ph = 2.0 * PI * ip / 5.0;
            const double st = std::sqrt(std::max(1.0 - ct * ct, 0.0));
            const double x = st * std::cos(ph), y = st * std::sin(ph), z = ct;
            DIRS[u][0] = x; DIRS[u][1] = y; DIRS[u][2] = z;
            double Y[9];
            Y[0] = 0.282095;           Y[1] = 0.488603 * y;      Y[2] = 0.488603 * z;
            Y[3] = 0.488603 * x;       Y[4] = 1.092548 * x * y;  Y[5] = 1.092548 * y * z;
            Y[6] = 0.315392 * (3 * z * z - 1); Y[7] = 1.092548 * x * z; Y[8] = 0.546274 * (x * x - y * y);
            for (int e = 0; e < 9; e++) YW[e][u] = Y[e] * wq;
        }
        double RRED[9][9][9];
        for (int i = 0; i < 9; i++) for (int j = 0; j < 9; j++) for (int k = 0; k < 9; k++) RRED[i][j][k] = 0.0;
        const int off[3] = {0, 1, 4};
        double cnt[3] = {0, 0, 0};
        double rc[5][5][5];
        for (int l1 = 0; l1 <= 2; l1++) for (int l2 = 0; l2 <= 2; l2++) {
            const int Llo = std::abs(l1 - l2), Lhi = std::min(l1 + l2, 2);
            for (int L = Llo; L <= Lhi; L++) {
                real_cg_f(l1, l2, L, rc);
                for (int i1 = 0; i1 < 2 * l1 + 1; i1++)
                    for (int i2 = 0; i2 < 2 * l2 + 1; i2++)
                        for (int i3 = 0; i3 < 2 * L + 1; i3++)
                            RRED[off[l1] + i1][off[l2] + i2][off[L] + i3] += rc[i1][i2][i3];
                cnt[L] += 1.0;
            }
        }
        for (int L = 0; L <= 2; L++) {
            const double dv = std::max(cnt[L], 1.0);
            for (int a1 = 0; a1 < 9; a1++) for (int b = 0; b < 9; b++)
                for (int k = 0; k < 2 * L + 1; k++) RRED[a1][b][off[L] + k] /= dv;
        }
        for (int e = 0; e < 9; e++) for (int u = 0; u < 25; u++) h_const[e * 25 + u] = (float)YW[e][u];
        for (int e = 0; e < 9; e++) for (int l = 0; l < 9; l++) for (int m = 0; m < 9; m++)
            h_const[225 + e * 81 + l * 9 + m] = (float)RRED[e][l][m];
        for (int u = 0; u < 25; u++) for (int ax = 0; ax < 3; ax++) h_const[954 + u * 3 + ax] = (float)DIRS[u][ax];
        if (hipMalloc((void**)&d_const_g, 1029 * sizeof(float)) == hipSuccess)
            hipMemcpy(d_const_g, h_const, 1029 * sizeof(float), hipMemcpyHostToDevice);
    }
} g_init;

} // namespace

// ============================== device kernels ==============================

// R[n][p][c]: p=0 -> feat(l=0); p=1 -> |l=1 block|; p=2 -> |l=2 block|
__global__ void radial_k(const float* __restrict__ feat, float* __restrict__ R) {
    const int n = blockIdx.x, c = threadIdx.x;
    const float* f = feat + (size_t)n * 9 * 256 + c;
    const float f0 = f[0];
    const float a1 = f[256], a2 = f[512], a3 = f[768];
    const float b1 = f[1024], b2 = f[1280], b3 = f[1536], b4 = f[1792], b5 = f[2048];
    const float r1 = sqrtf(a1 * a1 + a2 * a2 + a3 * a3 + 1e-8f);
    const float r2 = sqrtf(b1 * b1 + b2 * b2 + b3 * b3 + b4 * b4 + b5 * b5 + 1e-8f);
    float* o = R + (size_t)n * 768 + c;
    o[0] = f0; o[256] = r1; o[512] = r2;
}

// fused Q/K projection GEMM (f16 MFMA): A = R (2048x768), B = Wq or Wk (768x256)
// grid (8, 32): x<4 -> Wq cols (cb=x*64), epilogue elu+1 -> qf row-major f32
//               x>=4 -> Wk cols (cb=(x-4)*64), epilogue elu+1 -> kfA frag f16
__global__ __launch_bounds__(256) void qk_gemm_k(const float* __restrict__ A,
                                                 const float* __restrict__ Wq,
                                                 const float* __restrict__ Wk,
                                                 float* __restrict__ qf,
                                                 _Float16* __restrict__ kfA) {
    __shared__ __align__(16) _Float16 Af[64 * 40];
    __shared__ __align__(16) _Float16 Bf[64 * 40];
    const int tid = threadIdx.x;
    const int w = tid >> 6, lane = tid & 63;
    const int l15 = lane & 15, quad = lane >> 4;
    const bool isK = blockIdx.x >= 4;
    const int cb = (blockIdx.x & 3) * 64;
    const int rb = blockIdx.y * 64;
    const float* B = isK ? Wk : Wq;
    const int N = 256, Kd = 768;
    const int sr = tid >> 2, sq = tid & 3;

    float4v acc[4];
#pragma unroll
    for (int s = 0; s < 4; s++) acc[s] = float4v{0.f, 0.f, 0.f, 0.f};

    for (int k0 = 0; k0 < Kd; k0 += 32) {
        __syncthreads();
        {
            const float* Ap = A + (size_t)(rb + sr) * Kd + k0 + sq * 8;
            const float4 a0 = *(const float4*)(Ap);
            const float4 a1 = *(const float4*)(Ap + 4);
            half8 hv;
            hv[0] = (_Float16)a0.x; hv[1] = (_Float16)a0.y; hv[2] = (_Float16)a0.z; hv[3] = (_Float16)a0.w;
            hv[4] = (_Float16)a1.x; hv[5] = (_Float16)a1.y; hv[6] = (_Float16)a1.z; hv[7] = (_Float16)a1.w;
            *(half8*)&Af[sr * 40 + sq * 8] = hv;
        }
        {
            const float* Bp = B + (size_t)(k0 + sq * 8) * N + cb + sr;
            half8 hv;
#pragma unroll
            for (int i = 0; i < 8; i++) hv[i] = (_Float16)Bp[(size_t)i * N];
            *(half8*)&Bf[sr * 40 + sq * 8] = hv;
        }
        __syncthreads();
        const half8 af = *(const half8*)&Af[(w * 16 + l15) * 40 + quad * 8];
#pragma unroll
        for (int s = 0; s < 4; s++) {
            const half8 bf = *(const half8*)&Bf[(s * 16 + l15) * 40 + quad * 8];
            acc[s] = __builtin_amdgcn_mfma_f32_16x16x32_f16(af, bf, acc[s], 0, 0, 0);
        }
    }
#pragma unroll
    for (int s = 0; s < 4; s++) {
#pragma unroll
        for (int r = 0; r < 4; r++) {
            const int row = rb + w * 16 + quad * 4 + r;
            const int col = cb + s * 16 + l15;
            float val = acc[s][r];
            val = (val > 0.f ? val : expf(val) - 1.f) + 1.f;
            if (isK) {
                const int hh = col >> 5, dd = col & 31, tt = dd >> 4, ll = dd & 15;
                kfA[(size_t)hh * 65536 + (size_t)(row >> 5) * 1024 + tt * 512 + ll * 32 + (row & 31)] = (_Float16)val;
            } else {
                qf[(size_t)row * 256 + col] = val;
            }
        }
    }
}

// f16 MFMA GEMM, C = A(MxK) @ B(KxN), M%64==0, N%64==0, K%32==0.
// mode 2: v16T f16 scatter
// mode 4: A = sum of 4 partial buffers (stride 2359296 floats) scaled by rZ[n][h];
//         plain f32 C row-major
__global__ __launch_bounds__(256) void mfma_gemm16_k(const float* __restrict__ A, const float* __restrict__ B,
                                                     float* __restrict__ Cv, int M, int N, int Kd, int mode,
                                                     const float* __restrict__ rZ) {
    __shared__ __align__(16) _Float16 Af[64 * 40];   // [row][k], stride 40 halves (80 B)
    __shared__ __align__(16) _Float16 Bf[64 * 40];   // [col][k]
    const int tid = threadIdx.x;
    const int w = tid >> 6, lane = tid & 63;
    const int l15 = lane & 15, quad = lane >> 4;
    const int rb = blockIdx.y * 64, cb = blockIdx.x * 64;
    const int sr = tid >> 2, sq = tid & 3;           // stager: row/col 0..63, k-quartet 0..3

    float4v acc[4];
#pragma unroll
    for (int s = 0; s < 4; s++) acc[s] = float4v{0.f, 0.f, 0.f, 0.f};

    for (int k0 = 0; k0 < Kd; k0 += 32) {
        __syncthreads();
        // ---- stage A (f32 -> f16, fragment order) ----
        {
            const float* Ap = A + (size_t)(rb + sr) * Kd + k0 + sq * 8;
            float4 a0, a1;
            if (mode == 4) {
                const float4 p00 = *(const float4*)(Ap);
                const float4 p01 = *(const float4*)(Ap + 4);
                const float4 p10 = *(const float4*)(Ap + 2359296);
                const float4 p11 = *(const float4*)(Ap + 2359296 + 4);
                const float4 p20 = *(const float4*)(Ap + 4718592);
                const float4 p21 = *(const float4*)(Ap + 4718592 + 4);
                const float4 p30 = *(const float4*)(Ap + 7077888);
                const float4 p31 = *(const float4*)(Ap + 7077888 + 4);
                const int n = (rb + sr) / 9;
                const int hh = (k0 + sq * 8) >> 4;
                const float rz = rZ[n * 8 + hh];
                a0.x = (p00.x + p10.x + p20.x + p30.x) * rz;
                a0.y = (p00.y + p10.y + p20.y + p30.y) * rz;
                a0.z = (p00.z + p10.z + p20.z + p30.z) * rz;
                a0.w = (p00.w + p10.w + p20.w + p30.w) * rz;
                a1.x = (p01.x + p11.x + p21.x + p31.x) * rz;
                a1.y = (p01.y + p11.y + p21.y + p31.y) * rz;
                a1.z = (p01.z + p11.z + p21.z + p31.z) * rz;
                a1.w = (p01.w + p11.w + p21.w + p31.w) * rz;
            } else {
                a0 = *(const float4*)(Ap);
                a1 = *(const float4*)(Ap + 4);
            }
            half8 hv;
            hv[0] = (_Float16)a0.x; hv[1] = (_Float16)a0.y; hv[2] = (_Float16)a0.z; hv[3] = (_Float16)a0.w;
            hv[4] = (_Float16)a1.x; hv[5] = (_Float16)a1.y; hv[6] = (_Float16)a1.z; hv[7] = (_Float16)a1.w;
            *(half8*)&Af[sr * 40 + sq * 8] = hv;
        }
        // ---- stage B (column gather; f32 -> f16) ----
        {
            const float* Bp = B + (size_t)(k0 + sq * 8) * N + cb + sr;
            half8 hv;
#pragma unroll
            for (int i = 0; i < 8; i++) hv[i] = (_Float16)Bp[(size_t)i * N];
            *(half8*)&Bf[sr * 40 + sq * 8] = hv;
        }
        __syncthreads();
        // ---- fragments + MFMA ----
        const half8 af = *(const half8*)&Af[(w * 16 + l15) * 40 + quad * 8];
#pragma unroll
        for (int s = 0; s < 4; s++) {
            const half8 bf = *(const half8*)&Bf[(s * 16 + l15) * 40 + quad * 8];
            acc[s] = __builtin_amdgcn_mfma_f32_16x16x32_f16(af, bf, acc[s], 0, 0, 0);
        }
    }
    // ---- epilogue: C fragment (row = rb+w*16+quad*4+r, col = cb+s*16+l15) ----
#pragma unroll
    for (int s = 0; s < 4; s++) {
#pragma unroll
        for (int r = 0; r < 4; r++) {
            const int row = rb + w * 16 + quad * 4 + r;
            const int col = cb + s * 16 + l15;
            float val = acc[s][r];
            if (mode == 2) {
                // v16T[(h*144 + c*9 + l)][n] f16
                const int n = row / 9, l = row - n * 9, hq = col >> 4, cvq = col & 15;
                _Float16* o = (_Float16*)Cv;
                o[((size_t)hq * 144 + cvq * 9 + l) * 2048 + n] = (_Float16)val;
            } else {
                Cv[(size_t)row * N + col] = val;
            }
        }
    }
}

// trigA[nb5][kkut][j] (f16, fragment-ordered) = cos/sin(kappa_kk * pos_n . dir_u)
//   kkut = (kk*25+u)*2+t (rows, padded to 512), nb5 = n>>5, j = n&31
// threads 200..255 zero the pad rows 400..511 for this n's j-slot (replaces memset)
__global__ void trig_k(const float* __restrict__ pos, const float* __restrict__ kappa,
                       const float* __restrict__ cst, _Float16* __restrict__ trigA) {
    const int n = blockIdx.x, t = threadIdx.x;
    const size_t base = (size_t)(n >> 5) * 16384 + (n & 31);
    if (t < 200) {
        const int kq = t / 25, u = t - kq * 25;
        const float* dirs = cst + 954;
        const float ph = kappa[kq] * (pos[n * 3] * dirs[u * 3] + pos[n * 3 + 1] * dirs[u * 3 + 1] + pos[n * 3 + 2] * dirs[u * 3 + 2]);
        float s, c;
        sincosf(ph, &s, &c);
        const int kkut = (kq * 25 + u) * 2;
        trigA[base + (size_t)kkut * 32] = (_Float16)c;
        trigA[base + (size_t)(kkut + 1) * 32] = (_Float16)s;
    } else {
        const int kkut = 400 + (t - 200) * 2;
        trigA[base + (size_t)kkut * 32] = (_Float16)0.f;
        trigA[base + (size_t)(kkut + 1) * 32] = (_Float16)0.f;
    }
}

// ksum[h*32+d] = sum_n kfA[h][nb5][t][l15][j]; one block per (h,d)
__global__ void ksumT_k(const _Float16* __restrict__ kfA, float* __restrict__ ksum) {
    const int b = blockIdx.x;                       // h*32+d
    const int h = b >> 5, d = b & 31, t = d >> 4, l15 = d & 15;
    const int i = threadIdx.x;                      // 256
    const half8 v = *(const half8*)(kfA + (size_t)h * 65536 + (size_t)(i >> 2) * 1024 + t * 512 + l15 * 32 + (i & 3) * 8);
    float s = 0.f;
#pragma unroll
    for (int k = 0; k < 8; k++) s += (float)v[k];
#pragma unroll
    for (int off = 32; off > 0; off >>= 1) s += __shfl_down(s, off, 64);
    __shared__ float red[4];
    if ((i & 63) == 0) red[i >> 6] = s;
    __syncthreads();
    if (i == 0) ksum[b] = red[0] + red[1] + red[2] + red[3];
}

// merged z + g (block-range dispatch, 128 blocks):
//   blocks 0..63:  rz[n][h] = 1 / (qf[n,h,:].ksum[h,:] + 1e-6)
//   blocks 64..127: G[kk][h][u][l*9+m] = sum_e aE[e,h,kk]*YW[e,u]*RRED[e,l,m]
__global__ void zg_k(const float* __restrict__ qf, const float* __restrict__ ksum, float* __restrict__ rz,
                     const float* __restrict__ a, const float* __restrict__ cst, float* __restrict__ G) {
    if (blockIdx.x < 64) {
        const int idx = blockIdx.x * 256 + threadIdx.x;   // N*H = 16384
        const int n = idx >> 3, h = idx & 7;
        float s = 0.f;
#pragma unroll
        for (int d = 0; d < 32; d++) s += qf[(size_t)n * 256 + h * 32 + d] * ksum[h * 32 + d];
        rz[idx] = 1.0f / (s + 1e-6f);
    } else {
        const int b = blockIdx.x - 64;
        const int kk = b & 7, h = b >> 3;
        __shared__ float ae[9];
        if (threadIdx.x < 9) {
            const int ldeg[9] = {0, 1, 1, 1, 2, 2, 2, 2, 2};
            ae[threadIdx.x] = a[ldeg[threadIdx.x] * 64 + h * 8 + kk];
        }
        __syncthreads();
        const float* yw = cst;
        const float* rred = cst + 225;
        for (int i = threadIdx.x; i < 25 * 81; i += 256) {
            const int u = i / 81, lm = i - u * 81;
            float s = 0.f;
#pragma unroll
            for (int e = 0; e < 9; e++) s += ae[e] * yw[e * 25 + u] * rred[e * 81 + lm];
            G[((size_t)(kk * 8 + h) * 25 + u) * 81 + lm] = s;
        }
    }
}

// MFMA multipole, LDS-reduction K-split (R11) + XCD-h affinity (R12):
//   M16[kkut][h][cl*32+d] = sum_n trigA * kfA * v16T
// grid (8 h, 36 cl-quads, 4 row-blocks): linear block ID % 8 == h -> all blocks
// of head h land on XCD h; per-XCD hot read set 2.7 MB < 4 MB L2 (R12: FETCH 31->14 MB).
// block 512 = 8 waves; waves 0-3 rows rb..rb+127 over n in [0,1024),
// waves 4-7 same rows over n in [1024,2048).
__global__ __launch_bounds__(512) void multipole_mm_k(const _Float16* __restrict__ trigA,
                                                      const _Float16* __restrict__ kfA,
                                                      const _Float16* __restrict__ v16T,
                                                      _Float16* __restrict__ M16) {
    const int h   = blockIdx.x;
    const int cl0 = blockIdx.y * 4;          // 4 cl per block -> 128 cols
    const int cb  = blockIdx.y * 128;
    const int rb  = blockIdx.z * 128;        // rows (kkut, padded to 512)
    const int tid = threadIdx.x;
    const int w = tid >> 6, lane = tid & 63;
    const int wlow = w & 3, nsp = w >> 2;    // row-group, n-split half
    const int l15 = lane & 15, quad = lane >> 4;

    const int r0 = rb + wlow * 32;

    float4v acc[2][8];
#pragma unroll
    for (int rt = 0; rt < 2; rt++)
#pragma unroll
        for (int s = 0; s < 8; s++) acc[rt][s] = float4v{0.f, 0.f, 0.f, 0.f};

    const _Float16* tb_ = trigA + (size_t)(r0 + l15) * 32 + quad * 8;           // + nb*512 (slab), af1 +512
    const _Float16* kb_ = kfA + (size_t)h * 65536 + l15 * 32 + quad * 8;        // + nb5*1024, kq1 +512
    const _Float16* vp  = v16T + ((size_t)h * 144 + cl0) * 2048 + quad * 8;     // + c*2048 + nb (broadcast)

    const int nb0 = nsp * 1024, nb1 = nb0 + 1024;
    for (int nb = nb0; nb < nb1; nb += 32) {
        const size_t ts = (size_t)nb * 512;          // nb5 * 16384
        const size_t ks = (size_t)(nb >> 5) * 1024;
        const half8 af0 = *(const half8*)(tb_ + ts);
        const half8 af1 = *(const half8*)(tb_ + ts + 512);
        const half8 kq0 = *(const half8*)(kb_ + ks);
        const half8 kq1 = *(const half8*)(kb_ + ks + 512);
        half8 vq[4];
#pragma unroll
        for (int c = 0; c < 4; c++) vq[c] = *(const half8*)(vp + (size_t)c * 2048 + nb);
#pragma unroll
        for (int c = 0; c < 4; c++) {
            const half8 b0 = kq0 * vq[c];
            const half8 b1 = kq1 * vq[c];
            acc[0][c * 2 + 0] = __builtin_amdgcn_mfma_f32_16x16x32_f16(af0, b0, acc[0][c * 2 + 0], 0, 0, 0);
            acc[0][c * 2 + 1] = __builtin_amdgcn_mfma_f32_16x16x32_f16(af0, b1, acc[0][c * 2 + 1], 0, 0, 0);
            acc[1][c * 2 + 0] = __builtin_amdgcn_mfma_f32_16x16x32_f16(af1, b0, acc[1][c * 2 + 0], 0, 0, 0);
            acc[1][c * 2 + 1] = __builtin_amdgcn_mfma_f32_16x16x32_f16(af1, b1, acc[1][c * 2 + 1], 0, 0, 0);
        }
    }
    // ---- cross-wave reduction: upper waves -> LDS, lower waves add ----
    __shared__ float red[4][64][64];   // [wlow][idx][lane], 64 KB, bank-conflict-free
    if (nsp == 1) {
#pragma unroll
        for (int rt = 0; rt < 2; rt++)
#pragma unroll
            for (int s = 0; s < 8; s++)
#pragma unroll
                for (int r = 0; r < 4; r++)
                    red[wlow][rt * 32 + s * 4 + r][lane] = acc[rt][s][r];
    }
    __syncthreads();
    if (nsp == 0) {
#pragma unroll
        for (int rt = 0; rt < 2; rt++)
#pragma unroll
            for (int s = 0; s < 8; s++)
#pragma unroll
                for (int r = 0; r < 4; r++)
                    acc[rt][s][r] += red[wlow][rt * 32 + s * 4 + r][lane];
        // epilogue: C fragment -> M16[kkut][h][col]
#pragma unroll
        for (int rt = 0; rt < 2; rt++)
#pragma unroll
            for (int c = 0; c < 4; c++)
#pragma unroll
                for (int half = 0; half < 2; half++)
#pragma unroll
                    for (int r = 0; r < 4; r++) {
                        const int row = r0 + rt * 16 + quad * 4 + r;
                        const int col = cb + c * 32 + half * 16 + l15;
                        M16[((size_t)row * 8 + h) * 4608 + col] = (_Float16)acc[rt][c * 2 + half][r];
                    }
    }
}

// MG[kt][h][ct*512 + quad*128 + l15*8 + j] (f16, fragment-ordered)
//   = sum_l M16[kt][h][(c*9+l)*32+d] * G[kk,h,u][l*9+m], cm=ct*16+l15, d=quad*8+j
__global__ __launch_bounds__(256) void fold_k(const _Float16* __restrict__ Mv, const float* __restrict__ G,
                                              _Float16* __restrict__ MG) {
    const int kt = blockIdx.x, h = blockIdx.y;
    const int tid = threadIdx.x;
    __shared__ float ms[144 * 33];   // [cl][d] padded 33
    __shared__ float gs[81];
    const _Float16* src = Mv + ((size_t)kt * 8 + h) * 4608;
    for (int i = tid; i < 4608; i += 256) {
        const int cl = i >> 5, d = i & 31;
        ms[cl * 33 + d] = (float)src[i];
    }
    const int kk = kt / 50, u = (kt >> 1) % 25;
    if (tid < 81) gs[tid] = G[(((size_t)kk * 8 + h) * 25 + u) * 81 + tid];
    __syncthreads();
    _Float16* dst = MG + ((size_t)kt * 8 + h) * 4608;
    for (int i = tid; i < 4608; i += 256) {
        const int ct = i >> 9, quad = (i >> 7) & 3, l15 = (i >> 3) & 15, j = i & 7;
        const int d = quad * 8 + j;
        const int cm = ct * 16 + l15, c = cm / 9, m = cm - c * 9;
        float s = 0.f;
#pragma unroll
        for (int l = 0; l < 9; l++) s += ms[(c * 9 + l) * 33 + d] * gs[l * 9 + m];
        dst[i] = (_Float16)s;
    }
}

// local stage via MFMA, barrier-free main loop; slab loads contiguous-1KB;
// epilogue transposes fragments through per-wave LDS so every store is a
// full 64 B line. grid (8 slots, 4 comboHi, 16 ngroups): combo = h*4+slice ->
// same XCD per (h,slice); per-XCD MG set 3.7 MB < 4 MB L2 (R8).
__global__ __launch_bounds__(256) void mm_local_k(const float* __restrict__ qf, const _Float16* __restrict__ trigA,
                                                  const _Float16* __restrict__ MG, float* __restrict__ outp) {
    const int combo = blockIdx.y * 8 + blockIdx.x;
    const int h = combo >> 2;
    const int slice = combo & 3;
    const int n0 = blockIdx.z * 128;
    const int tid = threadIdx.x;
    const int w = tid >> 6, lane = tid & 63;
    const int l15 = lane & 15, quad = lane >> 4;

    const int nbase = n0 + w * 32;
    half8 qfr16[2];
#pragma unroll
    for (int rt = 0; rt < 2; rt++) {
        const int n = nbase + rt * 16 + l15;
        const float* qp = qf + (size_t)n * 256 + h * 32 + quad * 8;
#pragma unroll
        for (int j = 0; j < 8; j++) qfr16[rt][j] = (_Float16)qp[j];
    }
    float4v acc[2][9];
#pragma unroll
    for (int rt = 0; rt < 2; rt++)
#pragma unroll
        for (int ct = 0; ct < 9; ct++) acc[rt][ct] = float4v{0.f, 0.f, 0.f, 0.f};

    const int kt0 = slice * 100;
    const _Float16* slab0 = MG + (((size_t)kt0 * 8 + h) * 4608) + quad * 128 + l15 * 8;
    // trig scalars: trigA[nb5][kt][rt*16+l15]
    const _Float16* trg0 = trigA + (size_t)(nbase >> 5) * 16384 + (size_t)kt0 * 32 + l15;

    for (int kt = 0; kt < 100; kt++) {
        const _Float16* slab = slab0 + (size_t)kt * 8 * 4608;
        const _Float16 tv0 = trg0[(size_t)kt * 32];
        const _Float16 tv1 = trg0[(size_t)kt * 32 + 16];
        half8 tvv0, tvv1;
#pragma unroll
        for (int j = 0; j < 8; j++) { tvv0[j] = tv0; tvv1[j] = tv1; }
        const half8 af0 = tvv0 * qfr16[0];
        const half8 af1 = tvv1 * qfr16[1];
#pragma unroll
        for (int ct = 0; ct < 9; ct++) {
            const half8 b = *(const half8*)(slab + ct * 512);
            acc[0][ct] = __builtin_amdgcn_mfma_f32_16x16x32_f16(af0, b, acc[0][ct], 0, 0, 0);
            acc[1][ct] = __builtin_amdgcn_mfma_f32_16x16x32_f16(af1, b, acc[1][ct], 0, 0, 0);
        }
    }
    // epilogue: LDS transpose -> full-line stores into outp[slice][n][m][h][c]
    __shared__ float eb[4][16][148];   // per-wave [n_local][m*16+c], pad 148 (16B-aligned rows)
    float* dst = outp + (size_t)slice * 2359296;
    const int g4 = lane >> 2, sub = lane & 3;
#pragma unroll
    for (int rt = 0; rt < 2; rt++) {
        __syncthreads();
#pragma unroll
        for (int ct = 0; ct < 9; ct++) {
            const int cm = ct * 16 + l15;
            const int c = cm / 9, m = cm - c * 9;
#pragma unroll
            for (int r = 0; r < 4; r++)
                eb[w][quad * 4 + r][m * 16 + c] = acc[rt][ct][r];
        }
        __syncthreads();
#pragma unroll
        for (int s = 0; s < 9; s++) {
            const int li = s * 16 + g4;            // 0..143 line index
            const int nl = li / 9, m = li - nl * 9;
            const float4 v4 = *(const float4*)&eb[w][nl][m * 16 + sub * 4];
            const int n = nbase + rt * 16 + nl;
            *(float4*)&dst[((size_t)n * 9 + m) * 128 + h * 16 + sub * 4] = v4;
        }
    }
}

// ================================ launcher =================================
extern "C" void kernel_launch(void* const* d_in, const int* in_sizes, int n_in,
                              void* d_out, int out_size, void* d_ws, size_t ws_size,
                              hipStream_t stream) {
    const float* pos  = (const float*)d_in[0];
    const float* feat = (const float*)d_in[1];
    const float* Wq   = (const float*)d_in[2];
    const float* Wk   = (const float*)d_in[3];
    const float* Wv   = (const float*)d_in[4];
    const float* Wo   = (const float*)d_in[5];
    const float* a    = (const float*)d_in[6];
    const float* kap  = (const float*)d_in[7];
    float* out = (float*)d_out;
    float* ws = (float*)d_ws;

    // float-slot layout (~77.8 MB total)
    float* qf    = ws;                    // 524288
    float* kfAF  = qf + 524288;           // 262144 slots = kfA f16[8][64][2][512]
    float* vTF   = kfAF + 262144;         // 1179648 slots = v16T f16[1152*2048]
    float* trigF = vTF + 1179648;         // 524288 slots = trigA f16[64][512][32]
    float* ksum  = trigF + 524288;        // 256
    float* rz    = ksum + 256;            // 16384
    float* G     = rz + 16384;            // 129600
    float* M16F  = G + 129600;            // 9437184 slots = M16 f16[512*8*4608]; later outp[4][2359296]
    float* regX  = M16F + 9437184;        // 7372800 slots: R (first 1572864), later MG f16[400*8*4608]
    float* R     = regX;
    float* outp  = M16F;                  // overlay: M16 dead after fold_k; 4 partial buffers
    _Float16* trigA = (_Float16*)trigF;
    _Float16* kfA   = (_Float16*)kfAF;
    _Float16* v16T  = (_Float16*)vTF;
    _Float16* M16   = (_Float16*)M16F;
    _Float16* MG16  = (_Float16*)regX;

    const float* cst = d_const_g;

    hipLaunchKernelGGL(radial_k, dim3(2048), dim3(256), 0, stream, feat, R);
    hipLaunchKernelGGL(qk_gemm_k, dim3(8, 32), dim3(256), 0, stream, R, Wq, Wk, qf, kfA);
    hipLaunchKernelGGL(mfma_gemm16_k, dim3(2, 288), dim3(256), 0, stream, feat, Wv, vTF, 18432, 128, 256, 2, rz);
    hipLaunchKernelGGL(trig_k, dim3(2048), dim3(256), 0, stream, pos, kap, cst, trigA);
    hipLaunchKernelGGL(ksumT_k, dim3(256), dim3(256), 0, stream, kfA, ksum);
    hipLaunchKernelGGL(zg_k, dim3(128), dim3(256), 0, stream, qf, ksum, rz, a, cst, G);
    hipLaunchKernelGGL(multipole_mm_k, dim3(8, 36, 4), dim3(512), 0, stream, trigA, kfA, v16T, M16);
    hipLaunchKernelGGL(fold_k, dim3(400, 8), dim3(256), 0, stream, M16, G, MG16);
    hipLaunchKernelGGL(mm_local_k, dim3(8, 4, 16), dim3(256), 0, stream, qf, trigA, MG16, outp);
    hipLaunchKernelGGL(mfma_gemm16_k, dim3(4, 288), dim3(256), 0, stream, outp, Wo, out, 18432, 256, 128, 4, rz);
}